// Round 2
// baseline (746.403 us; speedup 1.0000x reference)
//
#include <hip/hip_runtime.h>
#include <hip/hip_bf16.h>

typedef unsigned short u16;
typedef unsigned int u32;

typedef short short8 __attribute__((ext_vector_type(8)));
typedef float f32x4 __attribute__((ext_vector_type(4)));

// ---------------- problem constants ----------------
constexpr int Bc   = 8;
constexpr int Nc   = 2048;
constexpr int DIMc = 1024;
constexpr int Ec   = 8;
constexpr int HIDc = 2048;
constexpr int CAPc = 512;
constexpr int NTOK   = Bc * Nc;        // 16384
constexpr int SLOTPE = Bc * CAPc;      // 4096 slots per expert
constexpr int NSLOT  = Ec * SLOTPE;    // 32768

// ---------------- misc ws layout (bytes, fixed 1 MiB block) ----------------
constexpr size_t OFF_SLOTTOK = 0;                       // NSLOT*4   = 128 KiB
constexpr size_t OFF_SGATE   = OFF_SLOTTOK + (size_t)NSLOT * 4;   // 128 KiB
constexpr size_t OFF_G1      = OFF_SGATE + (size_t)NSLOT * 4;     // 64 KiB
constexpr size_t OFF_G2      = OFF_G1 + (size_t)NTOK * 4;
constexpr size_t OFF_META    = OFF_G2 + (size_t)NTOK * 4;
constexpr size_t OFF_RAW     = OFF_META + (size_t)NTOK * 4;       // 512 KiB
constexpr size_t OFF_S       = OFF_RAW + (size_t)NTOK * 8 * 4;
constexpr size_t OFF_C       = OFF_S + 64 * 4;
constexpr size_t MISC_END    = 1 << 20;                 // 1 MiB
static_assert(OFF_C + 64 * 4 <= MISC_END, "misc overflow");

constexpr size_t SZ_W1T_E = (size_t)HIDc * DIMc * 2;    // 4 MiB
constexpr size_t SZ_W2T_E = (size_t)DIMc * HIDc * 2;    // 4 MiB
constexpr size_t SZ_EI_E  = (size_t)SLOTPE * DIMc * 2;  // 8 MiB
constexpr size_t SZ_HID_E = (size_t)SLOTPE * HIDc * 2;  // 16 MiB
constexpr size_t SZ_PER_E = SZ_W1T_E + SZ_W2T_E + SZ_EI_E + SZ_HID_E; // 32 MiB

// ---------------- helpers ----------------
__device__ inline u16 f2bf(float f) {
    u32 u = __float_as_uint(f);
    u32 r = (u + 0x7fffu + ((u >> 16) & 1u)) >> 16;
    return (u16)r;
}
__device__ inline u32 pack2(float lo, float hi) {
    return (u32)f2bf(lo) | ((u32)f2bf(hi) << 16);
}

#define GLDS16(gp, lp)                                                          \
    __builtin_amdgcn_global_load_lds(                                          \
        (const __attribute__((address_space(1))) void*)(gp),                   \
        (__attribute__((address_space(3))) void*)(lp), 16, 0, 0)

// ---------------- zero d_out (harness poisons with 0xAA) ----------------
__global__ __launch_bounds__(256) void zero_out_kernel(float* __restrict__ p) {
    const size_t i = ((size_t)blockIdx.x * 256 + threadIdx.x) * 4;
    float4 z = {0.f, 0.f, 0.f, 0.f};
    *(float4*)(p + i) = z;
}

// ---------------- init slot map ----------------
__global__ __launch_bounds__(256) void init_slots_kernel(int* __restrict__ slot_token) {
    int i = (blockIdx.x * 256 + threadIdx.x) * 4;
    slot_token[i] = -1; slot_token[i + 1] = -1; slot_token[i + 2] = -1; slot_token[i + 3] = -1;
}

// ---------------- gating: one wave per token ----------------
__global__ __launch_bounds__(256) void gate_kernel(
    const float* __restrict__ x, const float* __restrict__ wg,
    const float* __restrict__ rp, float* __restrict__ raw_out,
    float* __restrict__ g1_out, float* __restrict__ g2_out, int* __restrict__ meta_out)
{
    const int tk   = blockIdx.x * 4 + (threadIdx.x >> 6);
    const int lane = threadIdx.x & 63;
    const float* xr = x + (size_t)tk * DIMc;

    float acc[8] = {0.f, 0.f, 0.f, 0.f, 0.f, 0.f, 0.f, 0.f};
#pragma unroll
    for (int i = 0; i < 4; ++i) {
        const int d0 = i * 256 + lane * 4;
        float4 xv = *(const float4*)(xr + d0);
#pragma unroll
        for (int j = 0; j < 4; ++j) {
            float xs = (&xv.x)[j];
            float4 w0 = *(const float4*)(wg + (size_t)(d0 + j) * 8);
            float4 w1 = *(const float4*)(wg + (size_t)(d0 + j) * 8 + 4);
            acc[0] += xs * w0.x; acc[1] += xs * w0.y; acc[2] += xs * w0.z; acc[3] += xs * w0.w;
            acc[4] += xs * w1.x; acc[5] += xs * w1.y; acc[6] += xs * w1.z; acc[7] += xs * w1.w;
        }
    }
#pragma unroll
    for (int e = 0; e < 8; ++e) {
#pragma unroll
        for (int off = 1; off < 64; off <<= 1) acc[e] += __shfl_xor(acc[e], off);
    }

    if (lane == 0) {
        float mx = acc[0];
#pragma unroll
        for (int e = 1; e < 8; ++e) mx = fmaxf(mx, acc[e]);
        float ex[8], s = 0.f;
#pragma unroll
        for (int e = 0; e < 8; ++e) { ex[e] = expf(acc[e] - mx); s += ex[e]; }
        float inv = 1.f / s;
        float raw[8];
#pragma unroll
        for (int e = 0; e < 8; ++e) raw[e] = ex[e] * inv;

        int i1 = 0; float g1 = raw[0];
#pragma unroll
        for (int e = 1; e < 8; ++e) if (raw[e] > g1) { g1 = raw[e]; i1 = e; }
        int i2 = -1; float g2 = -1.f;
#pragma unroll
        for (int e = 0; e < 8; ++e) if (e != i1 && raw[e] > g2) { g2 = raw[e]; i2 = e; }

        float denom = g1 + g2 + 1e-9f;
        float g1n = g1 / denom, g2n = g2 / denom;
        int keep = (rp[tk] < (g2n / 0.2f)) ? 1 : 0;

        float* ro = raw_out + (size_t)tk * 8;
#pragma unroll
        for (int e = 0; e < 8; ++e) ro[e] = raw[e];
        g1_out[tk] = g1n;
        g2_out[tk] = g2n;
        meta_out[tk] = i1 | (i2 << 4) | (keep << 8);
    }
}

// ---------------- per-batch capacity scan ----------------
__global__ __launch_bounds__(256) void scan_kernel(
    const int* __restrict__ meta, const float* __restrict__ g1, const float* __restrict__ g2,
    int* __restrict__ slot_token, float* __restrict__ slot_gate)
{
    const int b = blockIdx.x;
    const int t = threadIdx.x;
    __shared__ int cnt[256][8];
    __shared__ int base_e[8];

    int m[8];
#pragma unroll
    for (int i = 0; i < 8; ++i) m[i] = meta[b * Nc + t * 8 + i];

    // ---- phase 1: first expert ----
    int c[8] = {0, 0, 0, 0, 0, 0, 0, 0};
#pragma unroll
    for (int i = 0; i < 8; ++i) c[m[i] & 15]++;
#pragma unroll
    for (int e = 0; e < 8; ++e) cnt[t][e] = c[e];
    __syncthreads();
    if (t < 8) {
        int run = 0;
        for (int i = 0; i < 256; ++i) { int v = cnt[i][t]; cnt[i][t] = run; run += v; }
        base_e[t] = run < CAPc ? run : CAPc;   // kept count = min(total, cap)
    }
    __syncthreads();
#pragma unroll
    for (int e = 0; e < 8; ++e) c[e] = cnt[t][e];
#pragma unroll
    for (int i = 0; i < 8; ++i) {
        const int tk = b * Nc + t * 8 + i;
        const int e = m[i] & 15;
        const int pos = c[e]++;
        if (pos < CAPc) {
            const int slot = ((e * Bc + b) << 9) | pos;
            slot_token[slot] = tk;
            slot_gate[slot]  = g1[tk];
        }
    }
    __syncthreads();

    // ---- phase 2: second expert ----
#pragma unroll
    for (int e = 0; e < 8; ++e) c[e] = 0;
#pragma unroll
    for (int i = 0; i < 8; ++i) {
        if ((m[i] >> 8) & 1) c[(m[i] >> 4) & 15]++;
    }
#pragma unroll
    for (int e = 0; e < 8; ++e) cnt[t][e] = c[e];
    __syncthreads();
    if (t < 8) {
        int run = 0;
        for (int i = 0; i < 256; ++i) { int v = cnt[i][t]; cnt[i][t] = run; run += v; }
    }
    __syncthreads();
#pragma unroll
    for (int e = 0; e < 8; ++e) c[e] = cnt[t][e];
#pragma unroll
    for (int i = 0; i < 8; ++i) {
        const int tk = b * Nc + t * 8 + i;
        if ((m[i] >> 8) & 1) {
            const int e = (m[i] >> 4) & 15;
            const int pos = base_e[e] + c[e]++;
            if (pos < CAPc) {
                const int slot = ((e * Bc + b) << 9) | pos;
                slot_token[slot] = tk;
                slot_gate[slot]  = g2[tk];
            }
        }
    }
}

// ---------------- loss reduction ----------------
__global__ __launch_bounds__(256) void reduce_stats_kernel(
    const float* __restrict__ raw, const int* __restrict__ meta,
    float* __restrict__ S, float* __restrict__ C)
{
    const int be = blockIdx.x, b = be >> 3, e = be & 7;
    float s = 0.f, c = 0.f;
    for (int n = threadIdx.x; n < Nc; n += 256) {
        const int tk = b * Nc + n;
        s += raw[(size_t)tk * 8 + e];
        c += ((meta[tk] & 15) == e) ? 1.f : 0.f;
    }
    __shared__ float sh_s[4], sh_c[4];
    const int lane = threadIdx.x & 63, wv = threadIdx.x >> 6;
#pragma unroll
    for (int off = 32; off; off >>= 1) { s += __shfl_down(s, off); c += __shfl_down(c, off); }
    if (lane == 0) { sh_s[wv] = s; sh_c[wv] = c; }
    __syncthreads();
    if (threadIdx.x == 0) {
        S[be] = sh_s[0] + sh_s[1] + sh_s[2] + sh_s[3];
        C[be] = sh_c[0] + sh_c[1] + sh_c[2] + sh_c[3];
    }
}

__global__ void loss_kernel(const float* __restrict__ S, const float* __restrict__ C,
                            float* __restrict__ dst)
{
    float v = S[threadIdx.x] * C[threadIdx.x];
#pragma unroll
    for (int off = 32; off; off >>= 1) v += __shfl_down(v, off);
    if (threadIdx.x == 0) *dst = v * (0.01f / ((float)Nc * (float)Nc));
}

// ---------------- weight transpose + bf16 convert (per round, e0 base) ----------------
template <int R, int C>
__global__ __launch_bounds__(256) void transpose_kernel(
    const float* __restrict__ w, u16* __restrict__ wT, const int e0)
{
    __shared__ float tile[32][33];
    const int ez = blockIdx.z;
    const int c0 = blockIdx.x * 32, r0 = blockIdx.y * 32;
    const float* src = w + (size_t)(e0 + ez) * R * C;
    u16* dst = wT + (size_t)ez * C * R;
    const int t = threadIdx.x;
#pragma unroll
    for (int i = 0; i < 4; ++i) {
        const int r = i * 8 + (t >> 5), cc = t & 31;
        tile[r][cc] = src[(size_t)(r0 + r) * C + c0 + cc];
    }
    __syncthreads();
#pragma unroll
    for (int i = 0; i < 4; ++i) {
        const int cc = i * 8 + (t >> 5), r = t & 31;
        dst[(size_t)(c0 + cc) * R + r0 + r] = f2bf(tile[r][cc]);
    }
}

// ---------------- gather tokens into expert-slot rows (bf16) ----------------
__global__ __launch_bounds__(256) void gather_kernel(
    const float* __restrict__ x, const int* __restrict__ slot_token,
    u16* __restrict__ ei, const int slot0)
{
    const int s = blockIdx.x * 4 + (threadIdx.x >> 6);
    const int lane = threadIdx.x & 63;
    const int tk = slot_token[slot0 + s];
    uint4* dst = (uint4*)(ei + ((size_t)s << 10)) + lane * 2;
    if (tk < 0) {
        uint4 z = {0u, 0u, 0u, 0u};
        dst[0] = z; dst[1] = z;
    } else {
        const float4* src = (const float4*)(x + ((size_t)tk << 10)) + lane * 4;
        float4 v0 = src[0], v1 = src[1], v2 = src[2], v3 = src[3];
        uint4 o0, o1;
        o0.x = pack2(v0.x, v0.y); o0.y = pack2(v0.z, v0.w);
        o0.z = pack2(v1.x, v1.y); o0.w = pack2(v1.z, v1.w);
        o1.x = pack2(v2.x, v2.y); o1.y = pack2(v2.z, v2.w);
        o1.z = pack2(v3.x, v3.y); o1.w = pack2(v3.z, v3.w);
        dst[0] = o0; dst[1] = o1;
    }
}

// ---------------- bf16 MFMA GEMM ----------------
// C[M,ldc] = A[M,K] * Bt[e][nB,K]^T.  128x128 tile, BK=64, 4 waves, 16x16x32 MFMA.
// SCATTER=false: bf16 store (optional exact gelu).
// SCATTER=true : out[tok*DIM + col] += slot_gate * acc  (f32 atomic).
template <int K, bool GELU, bool SCATTER>
__global__ __launch_bounds__(256) void gemm_kernel(
    const u16* __restrict__ A, const u16* __restrict__ Bt, u16* __restrict__ Cc,
    float* __restrict__ outf, const int* __restrict__ slot_token,
    const float* __restrict__ slot_gate, const int slot_base,
    const int nB, const int ldc)
{
    __shared__ u16 As[128 * 64];
    __shared__ u16 Bs[128 * 64];

    const int tid = threadIdx.x;
    const int wv = tid >> 6, lane = tid & 63;
    const int m0 = blockIdx.x * 128, n0 = blockIdx.y * 128;
    const int e = blockIdx.x >> 5;   // 32 m-tiles (4096 rows) per expert
    const u16* Bbase = Bt + ((size_t)e * nB + n0) * K;

    const int wr = wv >> 1, wc = wv & 1;
    const int lr = lane & 15, lk = lane >> 4;
    const int rowA = lane >> 3, col8 = (lane & 7) * 8;

    f32x4 acc[4][4];
#pragma unroll
    for (int i = 0; i < 4; ++i)
#pragma unroll
        for (int j = 0; j < 4; ++j) acc[i][j] = (f32x4)0.f;

    for (int k0 = 0; k0 < K; k0 += 64) {
        __syncthreads();
#pragma unroll
        for (int i = 0; i < 4; ++i) {
            const int g = i * 4 + wv;
            const u16* ga = A + (size_t)(m0 + g * 8 + rowA) * K + k0 + col8;
            GLDS16(ga, As + g * 512);
            const u16* gb = Bbase + (size_t)(g * 8 + rowA) * K + k0 + col8;
            GLDS16(gb, Bs + g * 512);
        }
        __syncthreads();

#pragma unroll
        for (int kk = 0; kk < 2; ++kk) {
            short8 a[4], b[4];
#pragma unroll
            for (int f = 0; f < 4; ++f) {
                a[f] = *(const short8*)(As + (wr * 64 + f * 16 + lr) * 64 + kk * 32 + lk * 8);
                b[f] = *(const short8*)(Bs + (wc * 64 + f * 16 + lr) * 64 + kk * 32 + lk * 8);
            }
#pragma unroll
            for (int fm = 0; fm < 4; ++fm)
#pragma unroll
                for (int fn = 0; fn < 4; ++fn)
                    acc[fm][fn] = __builtin_amdgcn_mfma_f32_16x16x32_bf16(
                        a[fm], b[fn], acc[fm][fn], 0, 0, 0);
        }
    }

#pragma unroll
    for (int fm = 0; fm < 4; ++fm) {
        const int row = m0 + wr * 64 + fm * 16 + lk * 4;
        if (SCATTER) {
            int tks[4]; float gs[4];
#pragma unroll
            for (int r = 0; r < 4; ++r) {
                const int sg = slot_base + row + r;
                tks[r] = slot_token[sg];
                gs[r]  = slot_gate[sg];
            }
#pragma unroll
            for (int fn = 0; fn < 4; ++fn) {
                const int col = n0 + wc * 64 + fn * 16 + lr;
#pragma unroll
                for (int r = 0; r < 4; ++r) {
                    if (tks[r] >= 0)
                        unsafeAtomicAdd(outf + ((size_t)tks[r] << 10) + col,
                                        gs[r] * acc[fm][fn][r]);
                }
            }
        } else {
#pragma unroll
            for (int fn = 0; fn < 4; ++fn) {
                const int col = n0 + wc * 64 + fn * 16 + lr;
#pragma unroll
                for (int r = 0; r < 4; ++r) {
                    float v = acc[fm][fn][r];
                    if (GELU) v = 0.5f * v * (1.f + erff(v * 0.70710678118654752f));
                    Cc[(size_t)(row + r) * ldc + col] = f2bf(v);
                }
            }
        }
    }
}

// ---------------- launch ----------------
extern "C" void kernel_launch(void* const* d_in, const int* in_sizes, int n_in,
                              void* d_out, int out_size, void* d_ws, size_t ws_size,
                              hipStream_t stream)
{
    (void)in_sizes; (void)n_in; (void)out_size;

    const float* x  = (const float*)d_in[0];
    const float* wg = (const float*)d_in[1];
    const float* w1 = (const float*)d_in[2];
    const float* w2 = (const float*)d_in[3];
    const float* rp = (const float*)d_in[4];
    float* out = (float*)d_out;
    char* ws = (char*)d_ws;

    // pick experts-per-round that fits ws_size (ws_size is fixed -> deterministic)
    int epr = 8;
    while (epr > 1 && MISC_END + (size_t)epr * SZ_PER_E > ws_size) epr >>= 1;
    if (MISC_END + SZ_PER_E > ws_size) return;  // < 33 MiB: cannot run

    int* slot_token = (int*)(ws + OFF_SLOTTOK);
    float* slot_gate = (float*)(ws + OFF_SGATE);
    float* g1 = (float*)(ws + OFF_G1);
    float* g2 = (float*)(ws + OFF_G2);
    int* meta = (int*)(ws + OFF_META);
    float* raw = (float*)(ws + OFF_RAW);
    float* Sr = (float*)(ws + OFF_S);
    float* C1 = (float*)(ws + OFF_C);

    u16* w1T = (u16*)(ws + MISC_END);
    u16* w2T = (u16*)(ws + MISC_END + (size_t)epr * SZ_W1T_E);
    u16* ei  = (u16*)(ws + MISC_END + (size_t)epr * (SZ_W1T_E + SZ_W2T_E));
    u16* hid = (u16*)(ws + MISC_END + (size_t)epr * (SZ_W1T_E + SZ_W2T_E + SZ_EI_E));

    zero_out_kernel<<<(size_t)NTOK * DIMc / 1024, 256, 0, stream>>>(out);
    init_slots_kernel<<<NSLOT / 1024, 256, 0, stream>>>(slot_token);
    gate_kernel<<<NTOK / 4, 256, 0, stream>>>(x, wg, rp, raw, g1, g2, meta);
    scan_kernel<<<Bc, 256, 0, stream>>>(meta, g1, g2, slot_token, slot_gate);
    reduce_stats_kernel<<<64, 256, 0, stream>>>(raw, meta, Sr, C1);
    loss_kernel<<<1, 64, 0, stream>>>(Sr, C1, out + (size_t)NTOK * DIMc);

    for (int e0 = 0; e0 < Ec; e0 += epr) {
        transpose_kernel<DIMc, HIDc><<<dim3(HIDc / 32, DIMc / 32, epr), 256, 0, stream>>>(
            w1, w1T, e0);
        transpose_kernel<HIDc, DIMc><<<dim3(DIMc / 32, HIDc / 32, epr), 256, 0, stream>>>(
            w2, w2T, e0);
        gather_kernel<<<epr * SLOTPE / 4, 256, 0, stream>>>(x, slot_token, ei, e0 * SLOTPE);

        gemm_kernel<DIMc, true, false><<<dim3(epr * 32, HIDc / 128), 256, 0, stream>>>(
            ei, w1T, hid, nullptr, nullptr, nullptr, 0, HIDc, HIDc);
        gemm_kernel<HIDc, false, true><<<dim3(epr * 32, DIMc / 128), 256, 0, stream>>>(
            hid, w2T, nullptr, out, slot_token, slot_gate, e0 * SLOTPE, DIMc, DIMc);
    }
}

// Round 3
// 700.596 us; speedup vs baseline: 1.0654x; 1.0654x over previous
//
#include <hip/hip_runtime.h>
#include <hip/hip_bf16.h>

typedef unsigned short u16;
typedef unsigned int u32;

typedef short short8 __attribute__((ext_vector_type(8)));
typedef float f32x4 __attribute__((ext_vector_type(4)));

// ---------------- problem constants ----------------
constexpr int Bc   = 8;
constexpr int Nc   = 2048;
constexpr int DIMc = 1024;
constexpr int Ec   = 8;
constexpr int HIDc = 2048;
constexpr int CAPc = 512;
constexpr int NTOK   = Bc * Nc;        // 16384
constexpr int SLOTPE = Bc * CAPc;      // 4096 slots per expert
constexpr int NSLOT  = Ec * SLOTPE;    // 32768

// ---------------- misc ws layout (bytes, fixed 1 MiB block) ----------------
constexpr size_t OFF_SLOTTOK = 0;
constexpr size_t OFF_SGATE   = OFF_SLOTTOK + (size_t)NSLOT * 4;
constexpr size_t OFF_G1      = OFF_SGATE + (size_t)NSLOT * 4;
constexpr size_t OFF_G2      = OFF_G1 + (size_t)NTOK * 4;
constexpr size_t OFF_META    = OFF_G2 + (size_t)NTOK * 4;
constexpr size_t OFF_RAW     = OFF_META + (size_t)NTOK * 4;
constexpr size_t OFF_S       = OFF_RAW + (size_t)NTOK * 8 * 4;
constexpr size_t OFF_C       = OFF_S + 64 * 4;
constexpr size_t MISC_END    = 1 << 20;
static_assert(OFF_C + 64 * 4 <= MISC_END, "misc overflow");

constexpr size_t SZ_W1T_E = (size_t)HIDc * DIMc * 2;    // 4 MiB
constexpr size_t SZ_W2T_E = (size_t)DIMc * HIDc * 2;    // 4 MiB
constexpr size_t SZ_EI_E  = (size_t)SLOTPE * DIMc * 2;  // 8 MiB
constexpr size_t SZ_HID_E = (size_t)SLOTPE * HIDc * 2;  // 16 MiB
constexpr size_t SZ_PER_E = SZ_W1T_E + SZ_W2T_E + SZ_EI_E + SZ_HID_E; // 32 MiB

// ---------------- helpers ----------------
__device__ inline u16 f2bf(float f) {
    u32 u = __float_as_uint(f);
    u32 r = (u + 0x7fffu + ((u >> 16) & 1u)) >> 16;
    return (u16)r;
}
__device__ inline u32 pack2(float lo, float hi) {
    return (u32)f2bf(lo) | ((u32)f2bf(hi) << 16);
}

#define GLDS16(gp, lp)                                                          \
    __builtin_amdgcn_global_load_lds(                                          \
        (const __attribute__((address_space(1))) void*)(gp),                   \
        (__attribute__((address_space(3))) void*)(lp), 16, 0, 0)

// ---------------- zero d_out ----------------
__global__ __launch_bounds__(256) void zero_out_kernel(float* __restrict__ p) {
    const size_t i = ((size_t)blockIdx.x * 256 + threadIdx.x) * 4;
    float4 z = {0.f, 0.f, 0.f, 0.f};
    *(float4*)(p + i) = z;
}

// ---------------- init slot map ----------------
__global__ __launch_bounds__(256) void init_slots_kernel(int* __restrict__ slot_token) {
    int i = (blockIdx.x * 256 + threadIdx.x) * 4;
    slot_token[i] = -1; slot_token[i + 1] = -1; slot_token[i + 2] = -1; slot_token[i + 3] = -1;
}

// ---------------- gating: one wave per token ----------------
__global__ __launch_bounds__(256) void gate_kernel(
    const float* __restrict__ x, const float* __restrict__ wg,
    const float* __restrict__ rp, float* __restrict__ raw_out,
    float* __restrict__ g1_out, float* __restrict__ g2_out, int* __restrict__ meta_out)
{
    const int tk   = blockIdx.x * 4 + (threadIdx.x >> 6);
    const int lane = threadIdx.x & 63;
    const float* xr = x + (size_t)tk * DIMc;

    float acc[8] = {0.f, 0.f, 0.f, 0.f, 0.f, 0.f, 0.f, 0.f};
#pragma unroll
    for (int i = 0; i < 4; ++i) {
        const int d0 = i * 256 + lane * 4;
        float4 xv = *(const float4*)(xr + d0);
#pragma unroll
        for (int j = 0; j < 4; ++j) {
            float xs = (&xv.x)[j];
            float4 w0 = *(const float4*)(wg + (size_t)(d0 + j) * 8);
            float4 w1 = *(const float4*)(wg + (size_t)(d0 + j) * 8 + 4);
            acc[0] += xs * w0.x; acc[1] += xs * w0.y; acc[2] += xs * w0.z; acc[3] += xs * w0.w;
            acc[4] += xs * w1.x; acc[5] += xs * w1.y; acc[6] += xs * w1.z; acc[7] += xs * w1.w;
        }
    }
#pragma unroll
    for (int e = 0; e < 8; ++e) {
#pragma unroll
        for (int off = 1; off < 64; off <<= 1) acc[e] += __shfl_xor(acc[e], off);
    }

    if (lane == 0) {
        float mx = acc[0];
#pragma unroll
        for (int e = 1; e < 8; ++e) mx = fmaxf(mx, acc[e]);
        float ex[8], s = 0.f;
#pragma unroll
        for (int e = 0; e < 8; ++e) { ex[e] = expf(acc[e] - mx); s += ex[e]; }
        float inv = 1.f / s;
        float raw[8];
#pragma unroll
        for (int e = 0; e < 8; ++e) raw[e] = ex[e] * inv;

        int i1 = 0; float g1 = raw[0];
#pragma unroll
        for (int e = 1; e < 8; ++e) if (raw[e] > g1) { g1 = raw[e]; i1 = e; }
        int i2 = -1; float g2 = -1.f;
#pragma unroll
        for (int e = 0; e < 8; ++e) if (e != i1 && raw[e] > g2) { g2 = raw[e]; i2 = e; }

        float denom = g1 + g2 + 1e-9f;
        float g1n = g1 / denom, g2n = g2 / denom;
        int keep = (rp[tk] < (g2n / 0.2f)) ? 1 : 0;

        float* ro = raw_out + (size_t)tk * 8;
#pragma unroll
        for (int e = 0; e < 8; ++e) ro[e] = raw[e];
        g1_out[tk] = g1n;
        g2_out[tk] = g2n;
        meta_out[tk] = i1 | (i2 << 4) | (keep << 8);
    }
}

// ---------------- per-batch capacity scan ----------------
__global__ __launch_bounds__(256) void scan_kernel(
    const int* __restrict__ meta, const float* __restrict__ g1, const float* __restrict__ g2,
    int* __restrict__ slot_token, float* __restrict__ slot_gate)
{
    const int b = blockIdx.x;
    const int t = threadIdx.x;
    __shared__ int cnt[256][8];
    __shared__ int base_e[8];

    int m[8];
#pragma unroll
    for (int i = 0; i < 8; ++i) m[i] = meta[b * Nc + t * 8 + i];

    int c[8] = {0, 0, 0, 0, 0, 0, 0, 0};
#pragma unroll
    for (int i = 0; i < 8; ++i) c[m[i] & 15]++;
#pragma unroll
    for (int e = 0; e < 8; ++e) cnt[t][e] = c[e];
    __syncthreads();
    if (t < 8) {
        int run = 0;
        for (int i = 0; i < 256; ++i) { int v = cnt[i][t]; cnt[i][t] = run; run += v; }
        base_e[t] = run < CAPc ? run : CAPc;
    }
    __syncthreads();
#pragma unroll
    for (int e = 0; e < 8; ++e) c[e] = cnt[t][e];
#pragma unroll
    for (int i = 0; i < 8; ++i) {
        const int tk = b * Nc + t * 8 + i;
        const int e = m[i] & 15;
        const int pos = c[e]++;
        if (pos < CAPc) {
            const int slot = ((e * Bc + b) << 9) | pos;
            slot_token[slot] = tk;
            slot_gate[slot]  = g1[tk];
        }
    }
    __syncthreads();

#pragma unroll
    for (int e = 0; e < 8; ++e) c[e] = 0;
#pragma unroll
    for (int i = 0; i < 8; ++i) {
        if ((m[i] >> 8) & 1) c[(m[i] >> 4) & 15]++;
    }
#pragma unroll
    for (int e = 0; e < 8; ++e) cnt[t][e] = c[e];
    __syncthreads();
    if (t < 8) {
        int run = 0;
        for (int i = 0; i < 256; ++i) { int v = cnt[i][t]; cnt[i][t] = run; run += v; }
    }
    __syncthreads();
#pragma unroll
    for (int e = 0; e < 8; ++e) c[e] = cnt[t][e];
#pragma unroll
    for (int i = 0; i < 8; ++i) {
        const int tk = b * Nc + t * 8 + i;
        if ((m[i] >> 8) & 1) {
            const int e = (m[i] >> 4) & 15;
            const int pos = base_e[e] + c[e]++;
            if (pos < CAPc) {
                const int slot = ((e * Bc + b) << 9) | pos;
                slot_token[slot] = tk;
                slot_gate[slot]  = g2[tk];
            }
        }
    }
}

// ---------------- loss reduction ----------------
__global__ __launch_bounds__(256) void reduce_stats_kernel(
    const float* __restrict__ raw, const int* __restrict__ meta,
    float* __restrict__ S, float* __restrict__ C)
{
    const int be = blockIdx.x, b = be >> 3, e = be & 7;
    float s = 0.f, c = 0.f;
    for (int n = threadIdx.x; n < Nc; n += 256) {
        const int tk = b * Nc + n;
        s += raw[(size_t)tk * 8 + e];
        c += ((meta[tk] & 15) == e) ? 1.f : 0.f;
    }
    __shared__ float sh_s[4], sh_c[4];
    const int lane = threadIdx.x & 63, wv = threadIdx.x >> 6;
#pragma unroll
    for (int off = 32; off; off >>= 1) { s += __shfl_down(s, off); c += __shfl_down(c, off); }
    if (lane == 0) { sh_s[wv] = s; sh_c[wv] = c; }
    __syncthreads();
    if (threadIdx.x == 0) {
        S[be] = sh_s[0] + sh_s[1] + sh_s[2] + sh_s[3];
        C[be] = sh_c[0] + sh_c[1] + sh_c[2] + sh_c[3];
    }
}

__global__ void loss_kernel(const float* __restrict__ S, const float* __restrict__ C,
                            float* __restrict__ dst)
{
    float v = S[threadIdx.x] * C[threadIdx.x];
#pragma unroll
    for (int off = 32; off; off >>= 1) v += __shfl_down(v, off);
    if (threadIdx.x == 0) *dst = v * (0.01f / ((float)Nc * (float)Nc));
}

// ---------------- weight transpose + bf16 convert ----------------
template <int R, int C>
__global__ __launch_bounds__(256) void transpose_kernel(
    const float* __restrict__ w, u16* __restrict__ wT, const int e0)
{
    __shared__ float tile[32][33];
    const int ez = blockIdx.z;
    const int c0 = blockIdx.x * 32, r0 = blockIdx.y * 32;
    const float* src = w + (size_t)(e0 + ez) * R * C;
    u16* dst = wT + (size_t)ez * C * R;
    const int t = threadIdx.x;
#pragma unroll
    for (int i = 0; i < 4; ++i) {
        const int r = i * 8 + (t >> 5), cc = t & 31;
        tile[r][cc] = src[(size_t)(r0 + r) * C + c0 + cc];
    }
    __syncthreads();
#pragma unroll
    for (int i = 0; i < 4; ++i) {
        const int cc = i * 8 + (t >> 5), r = t & 31;
        dst[(size_t)(c0 + cc) * R + r0 + r] = f2bf(tile[r][cc]);
    }
}

// ---------------- gather tokens into expert-slot rows (bf16) ----------------
__global__ __launch_bounds__(256) void gather_kernel(
    const float* __restrict__ x, const int* __restrict__ slot_token,
    u16* __restrict__ ei, const int slot0)
{
    const int s = blockIdx.x * 4 + (threadIdx.x >> 6);
    const int lane = threadIdx.x & 63;
    const int tk = slot_token[slot0 + s];
    uint4* dst = (uint4*)(ei + ((size_t)s << 10)) + lane * 2;
    if (tk < 0) {
        uint4 z = {0u, 0u, 0u, 0u};
        dst[0] = z; dst[1] = z;
    } else {
        const float4* src = (const float4*)(x + ((size_t)tk << 10)) + lane * 4;
        float4 v0 = src[0], v1 = src[1], v2 = src[2], v3 = src[3];
        uint4 o0, o1;
        o0.x = pack2(v0.x, v0.y); o0.y = pack2(v0.z, v0.w);
        o0.z = pack2(v1.x, v1.y); o0.w = pack2(v1.z, v1.w);
        o1.x = pack2(v2.x, v2.y); o1.y = pack2(v2.z, v2.w);
        o1.z = pack2(v3.x, v3.y); o1.w = pack2(v3.z, v3.w);
        dst[0] = o0; dst[1] = o1;
    }
}

// ---------------- 2-phase double-buffered 256x256 bf16 MFMA GEMM ----------------
// C[M,ldc] = A[M,K] * Bt[e][nB,K]^T. 8 waves (2x4), per-wave 128x64 output,
// BK=64, LDS 128 KiB (2 x (A 256x64 + B 256x64) bf16), STAGE(next) before
// compute(cur), one vmcnt(0)+barrier per K-tile.

template <int K>
__device__ inline void stage_tile(const u16* __restrict__ Ab, const u16* __restrict__ Bb,
                                  u16* As, u16* Bs, const int k0, const int tid)
{
    const int r  = tid >> 3;         // 0..63
    const int c8 = (tid & 7) * 8;    // element col (0..56)
#pragma unroll
    for (int i = 0; i < 4; ++i) {
        GLDS16(Ab + (size_t)(i * 64 + r) * K + k0 + c8, As + (i * 64 + r) * 64 + c8);
        GLDS16(Bb + (size_t)(i * 64 + r) * K + k0 + c8, Bs + (i * 64 + r) * 64 + c8);
    }
}

__device__ inline void compute_step(const u16* As, const u16* Bs,
                                    const int wr, const int wc, const int lr, const int lk,
                                    f32x4 acc[8][4])
{
#pragma unroll
    for (int kk = 0; kk < 2; ++kk) {
        short8 b[4];
#pragma unroll
        for (int fn = 0; fn < 4; ++fn)
            b[fn] = *(const short8*)(Bs + (wc * 64 + fn * 16 + lr) * 64 + kk * 32 + lk * 8);
#pragma unroll
        for (int fm = 0; fm < 8; ++fm) {
            short8 a = *(const short8*)(As + (wr * 128 + fm * 16 + lr) * 64 + kk * 32 + lk * 8);
#pragma unroll
            for (int fn = 0; fn < 4; ++fn)
                acc[fm][fn] = __builtin_amdgcn_mfma_f32_16x16x32_bf16(a, b[fn], acc[fm][fn], 0, 0, 0);
        }
    }
}

template <int K, bool GELU, bool SCATTER>
__device__ inline void gemm_body(
    const u16* __restrict__ A, const u16* __restrict__ Bt, u16* __restrict__ Cc,
    float* __restrict__ outf, const int* __restrict__ slot_token,
    const float* __restrict__ slot_gate, const int slot_base,
    const int nB, const int ldc)
{
    __shared__ u16 As[2][256 * 64];   // 64 KiB
    __shared__ u16 Bs[2][256 * 64];   // 64 KiB

    const int tid = threadIdx.x;
    const int wv = tid >> 6, lane = tid & 63;
    const int m0 = blockIdx.x * 256, n0 = blockIdx.y * 256;
    const int e = blockIdx.x >> 4;    // 16 m-tiles (4096 rows) per expert
    const u16* Ab = A + (size_t)m0 * K;
    const u16* Bb = Bt + ((size_t)e * nB + n0) * K;

    const int wr = wv >> 2, wc = wv & 3;
    const int lr = lane & 15, lk = lane >> 4;

    f32x4 acc[8][4];
#pragma unroll
    for (int i = 0; i < 8; ++i)
#pragma unroll
        for (int j = 0; j < 4; ++j) acc[i][j] = (f32x4)0.f;

    stage_tile<K>(Ab, Bb, As[0], Bs[0], 0, tid);
    asm volatile("s_waitcnt vmcnt(0)");
    __syncthreads();

    constexpr int NT = K / 64;
    int cur = 0;
    for (int kt = 0; kt < NT - 1; ++kt) {
        stage_tile<K>(Ab, Bb, As[cur ^ 1], Bs[cur ^ 1], (kt + 1) * 64, tid);
        __builtin_amdgcn_s_setprio(1);
        compute_step(As[cur], Bs[cur], wr, wc, lr, lk, acc);
        __builtin_amdgcn_s_setprio(0);
        asm volatile("s_waitcnt vmcnt(0)");
        __syncthreads();
        cur ^= 1;
    }
    compute_step(As[cur], Bs[cur], wr, wc, lr, lk, acc);

#pragma unroll
    for (int fm = 0; fm < 8; ++fm) {
        const int row = m0 + wr * 128 + fm * 16 + lk * 4;
        if (SCATTER) {
            int tks[4]; float gs[4];
#pragma unroll
            for (int r = 0; r < 4; ++r) {
                const int sg = slot_base + row + r;
                tks[r] = slot_token[sg];
                gs[r]  = slot_gate[sg];
            }
#pragma unroll
            for (int fn = 0; fn < 4; ++fn) {
                const int col = n0 + wc * 64 + fn * 16 + lr;
#pragma unroll
                for (int r = 0; r < 4; ++r) {
                    if (tks[r] >= 0)
                        unsafeAtomicAdd(outf + ((size_t)tks[r] << 10) + col,
                                        gs[r] * acc[fm][fn][r]);
                }
            }
        } else {
#pragma unroll
            for (int fn = 0; fn < 4; ++fn) {
                const int col = n0 + wc * 64 + fn * 16 + lr;
#pragma unroll
                for (int r = 0; r < 4; ++r) {
                    float v = acc[fm][fn][r];
                    if (GELU) v = 0.5f * v * (1.f + erff(v * 0.70710678118654752f));
                    Cc[(size_t)(row + r) * ldc + col] = f2bf(v);
                }
            }
        }
    }
}

__global__ __launch_bounds__(512, 2) void gemm1_kernel(
    const u16* __restrict__ A, const u16* __restrict__ Bt, u16* __restrict__ Cc)
{
    gemm_body<DIMc, true, false>(A, Bt, Cc, nullptr, nullptr, nullptr, 0, HIDc, HIDc);
}

__global__ __launch_bounds__(512, 2) void gemm2_kernel(
    const u16* __restrict__ A, const u16* __restrict__ Bt, float* __restrict__ outf,
    const int* __restrict__ slot_token, const float* __restrict__ slot_gate,
    const int slot_base)
{
    gemm_body<HIDc, false, true>(A, Bt, nullptr, outf, slot_token, slot_gate,
                                 slot_base, DIMc, DIMc);
}

// ---------------- launch ----------------
extern "C" void kernel_launch(void* const* d_in, const int* in_sizes, int n_in,
                              void* d_out, int out_size, void* d_ws, size_t ws_size,
                              hipStream_t stream)
{
    (void)in_sizes; (void)n_in; (void)out_size;

    const float* x  = (const float*)d_in[0];
    const float* wg = (const float*)d_in[1];
    const float* w1 = (const float*)d_in[2];
    const float* w2 = (const float*)d_in[3];
    const float* rp = (const float*)d_in[4];
    float* out = (float*)d_out;
    char* ws = (char*)d_ws;

    int epr = 8;
    while (epr > 1 && MISC_END + (size_t)epr * SZ_PER_E > ws_size) epr >>= 1;
    if (MISC_END + SZ_PER_E > ws_size) return;

    int* slot_token = (int*)(ws + OFF_SLOTTOK);
    float* slot_gate = (float*)(ws + OFF_SGATE);
    float* g1 = (float*)(ws + OFF_G1);
    float* g2 = (float*)(ws + OFF_G2);
    int* meta = (int*)(ws + OFF_META);
    float* raw = (float*)(ws + OFF_RAW);
    float* Sr = (float*)(ws + OFF_S);
    float* C1 = (float*)(ws + OFF_C);

    u16* w1T = (u16*)(ws + MISC_END);
    u16* w2T = (u16*)(ws + MISC_END + (size_t)epr * SZ_W1T_E);
    u16* ei  = (u16*)(ws + MISC_END + (size_t)epr * (SZ_W1T_E + SZ_W2T_E));
    u16* hid = (u16*)(ws + MISC_END + (size_t)epr * (SZ_W1T_E + SZ_W2T_E + SZ_EI_E));

    zero_out_kernel<<<(size_t)NTOK * DIMc / 1024, 256, 0, stream>>>(out);
    init_slots_kernel<<<NSLOT / 1024, 256, 0, stream>>>(slot_token);
    gate_kernel<<<NTOK / 4, 256, 0, stream>>>(x, wg, rp, raw, g1, g2, meta);
    scan_kernel<<<Bc, 256, 0, stream>>>(meta, g1, g2, slot_token, slot_gate);
    reduce_stats_kernel<<<64, 256, 0, stream>>>(raw, meta, Sr, C1);
    loss_kernel<<<1, 64, 0, stream>>>(Sr, C1, out + (size_t)NTOK * DIMc);

    for (int e0 = 0; e0 < Ec; e0 += epr) {
        transpose_kernel<DIMc, HIDc><<<dim3(HIDc / 32, DIMc / 32, epr), 256, 0, stream>>>(
            w1, w1T, e0);
        transpose_kernel<HIDc, DIMc><<<dim3(DIMc / 32, HIDc / 32, epr), 256, 0, stream>>>(
            w2, w2T, e0);
        gather_kernel<<<epr * SLOTPE / 4, 256, 0, stream>>>(x, slot_token, ei, e0 * SLOTPE);

        gemm1_kernel<<<dim3(epr * 16, HIDc / 256), 512, 0, stream>>>(ei, w1T, hid);
        gemm2_kernel<<<dim3(epr * 16, DIMc / 256), 512, 0, stream>>>(
            hid, w2T, out, slot_token, slot_gate, e0 * SLOTPE);
    }
}

// Round 4
// 674.662 us; speedup vs baseline: 1.1063x; 1.0384x over previous
//
#include <hip/hip_runtime.h>
#include <hip/hip_bf16.h>

typedef unsigned short u16;
typedef unsigned int u32;

typedef short short8 __attribute__((ext_vector_type(8)));
typedef float f32x4 __attribute__((ext_vector_type(4)));

// ---------------- problem constants ----------------
constexpr int Bc   = 8;
constexpr int Nc   = 2048;
constexpr int DIMc = 1024;
constexpr int Ec   = 8;
constexpr int HIDc = 2048;
constexpr int CAPc = 512;
constexpr int NTOK   = Bc * Nc;        // 16384
constexpr int SLOTPE = Bc * CAPc;      // 4096 slots per expert
constexpr int NSLOT  = Ec * SLOTPE;    // 32768

// ---------------- misc ws layout (bytes, fixed 1 MiB block) ----------------
constexpr size_t OFF_SLOTTOK = 0;
constexpr size_t OFF_SGATE   = OFF_SLOTTOK + (size_t)NSLOT * 4;
constexpr size_t OFF_G1      = OFF_SGATE + (size_t)NSLOT * 4;
constexpr size_t OFF_G2      = OFF_G1 + (size_t)NTOK * 4;
constexpr size_t OFF_META    = OFF_G2 + (size_t)NTOK * 4;
constexpr size_t OFF_RAW     = OFF_META + (size_t)NTOK * 4;
constexpr size_t OFF_S       = OFF_RAW + (size_t)NTOK * 8 * 4;
constexpr size_t OFF_C       = OFF_S + 64 * 4;
constexpr size_t MISC_END    = 1 << 20;
static_assert(OFF_C + 64 * 4 <= MISC_END, "misc overflow");

constexpr size_t SZ_W1T_E = (size_t)HIDc * DIMc * 2;    // 4 MiB
constexpr size_t SZ_W2T_E = (size_t)DIMc * HIDc * 2;    // 4 MiB
constexpr size_t SZ_EI_E  = (size_t)SLOTPE * DIMc * 2;  // 8 MiB
constexpr size_t SZ_HID_E = (size_t)SLOTPE * HIDc * 2;  // 16 MiB
constexpr size_t SZ_PER_E = SZ_W1T_E + SZ_W2T_E + SZ_EI_E + SZ_HID_E; // 32 MiB

// ---------------- helpers ----------------
__device__ inline u16 f2bf(float f) {
    u32 u = __float_as_uint(f);
    u32 r = (u + 0x7fffu + ((u >> 16) & 1u)) >> 16;
    return (u16)r;
}
__device__ inline u32 pack2(float lo, float hi) {
    return (u32)f2bf(lo) | ((u32)f2bf(hi) << 16);
}

#define GLDS16(gp, lp)                                                          \
    __builtin_amdgcn_global_load_lds(                                          \
        (const __attribute__((address_space(1))) void*)(gp),                   \
        (__attribute__((address_space(3))) void*)(lp), 16, 0, 0)

// ---------------- zero d_out ----------------
__global__ __launch_bounds__(256) void zero_out_kernel(float* __restrict__ p) {
    const size_t i = ((size_t)blockIdx.x * 256 + threadIdx.x) * 4;
    float4 z = {0.f, 0.f, 0.f, 0.f};
    *(float4*)(p + i) = z;
}

// ---------------- init slot map ----------------
__global__ __launch_bounds__(256) void init_slots_kernel(int* __restrict__ slot_token) {
    int i = (blockIdx.x * 256 + threadIdx.x) * 4;
    slot_token[i] = -1; slot_token[i + 1] = -1; slot_token[i + 2] = -1; slot_token[i + 3] = -1;
}

// ---------------- gating: one wave per token ----------------
__global__ __launch_bounds__(256) void gate_kernel(
    const float* __restrict__ x, const float* __restrict__ wg,
    const float* __restrict__ rp, float* __restrict__ raw_out,
    float* __restrict__ g1_out, float* __restrict__ g2_out, int* __restrict__ meta_out)
{
    const int tk   = blockIdx.x * 4 + (threadIdx.x >> 6);
    const int lane = threadIdx.x & 63;
    const float* xr = x + (size_t)tk * DIMc;

    float acc[8] = {0.f, 0.f, 0.f, 0.f, 0.f, 0.f, 0.f, 0.f};
#pragma unroll
    for (int i = 0; i < 4; ++i) {
        const int d0 = i * 256 + lane * 4;
        float4 xv = *(const float4*)(xr + d0);
#pragma unroll
        for (int j = 0; j < 4; ++j) {
            float xs = (&xv.x)[j];
            float4 w0 = *(const float4*)(wg + (size_t)(d0 + j) * 8);
            float4 w1 = *(const float4*)(wg + (size_t)(d0 + j) * 8 + 4);
            acc[0] += xs * w0.x; acc[1] += xs * w0.y; acc[2] += xs * w0.z; acc[3] += xs * w0.w;
            acc[4] += xs * w1.x; acc[5] += xs * w1.y; acc[6] += xs * w1.z; acc[7] += xs * w1.w;
        }
    }
#pragma unroll
    for (int e = 0; e < 8; ++e) {
#pragma unroll
        for (int off = 1; off < 64; off <<= 1) acc[e] += __shfl_xor(acc[e], off);
    }

    if (lane == 0) {
        float mx = acc[0];
#pragma unroll
        for (int e = 1; e < 8; ++e) mx = fmaxf(mx, acc[e]);
        float ex[8], s = 0.f;
#pragma unroll
        for (int e = 0; e < 8; ++e) { ex[e] = expf(acc[e] - mx); s += ex[e]; }
        float inv = 1.f / s;
        float raw[8];
#pragma unroll
        for (int e = 0; e < 8; ++e) raw[e] = ex[e] * inv;

        int i1 = 0; float g1 = raw[0];
#pragma unroll
        for (int e = 1; e < 8; ++e) if (raw[e] > g1) { g1 = raw[e]; i1 = e; }
        int i2 = -1; float g2 = -1.f;
#pragma unroll
        for (int e = 0; e < 8; ++e) if (e != i1 && raw[e] > g2) { g2 = raw[e]; i2 = e; }

        float denom = g1 + g2 + 1e-9f;
        float g1n = g1 / denom, g2n = g2 / denom;
        int keep = (rp[tk] < (g2n / 0.2f)) ? 1 : 0;

        float* ro = raw_out + (size_t)tk * 8;
#pragma unroll
        for (int e = 0; e < 8; ++e) ro[e] = raw[e];
        g1_out[tk] = g1n;
        g2_out[tk] = g2n;
        meta_out[tk] = i1 | (i2 << 4) | (keep << 8);
    }
}

// ---------------- per-batch capacity scan ----------------
__global__ __launch_bounds__(256) void scan_kernel(
    const int* __restrict__ meta, const float* __restrict__ g1, const float* __restrict__ g2,
    int* __restrict__ slot_token, float* __restrict__ slot_gate)
{
    const int b = blockIdx.x;
    const int t = threadIdx.x;
    __shared__ int cnt[256][8];
    __shared__ int base_e[8];

    int m[8];
#pragma unroll
    for (int i = 0; i < 8; ++i) m[i] = meta[b * Nc + t * 8 + i];

    int c[8] = {0, 0, 0, 0, 0, 0, 0, 0};
#pragma unroll
    for (int i = 0; i < 8; ++i) c[m[i] & 15]++;
#pragma unroll
    for (int e = 0; e < 8; ++e) cnt[t][e] = c[e];
    __syncthreads();
    if (t < 8) {
        int run = 0;
        for (int i = 0; i < 256; ++i) { int v = cnt[i][t]; cnt[i][t] = run; run += v; }
        base_e[t] = run < CAPc ? run : CAPc;
    }
    __syncthreads();
#pragma unroll
    for (int e = 0; e < 8; ++e) c[e] = cnt[t][e];
#pragma unroll
    for (int i = 0; i < 8; ++i) {
        const int tk = b * Nc + t * 8 + i;
        const int e = m[i] & 15;
        const int pos = c[e]++;
        if (pos < CAPc) {
            const int slot = ((e * Bc + b) << 9) | pos;
            slot_token[slot] = tk;
            slot_gate[slot]  = g1[tk];
        }
    }
    __syncthreads();

#pragma unroll
    for (int e = 0; e < 8; ++e) c[e] = 0;
#pragma unroll
    for (int i = 0; i < 8; ++i) {
        if ((m[i] >> 8) & 1) c[(m[i] >> 4) & 15]++;
    }
#pragma unroll
    for (int e = 0; e < 8; ++e) cnt[t][e] = c[e];
    __syncthreads();
    if (t < 8) {
        int run = 0;
        for (int i = 0; i < 256; ++i) { int v = cnt[i][t]; cnt[i][t] = run; run += v; }
    }
    __syncthreads();
#pragma unroll
    for (int e = 0; e < 8; ++e) c[e] = cnt[t][e];
#pragma unroll
    for (int i = 0; i < 8; ++i) {
        const int tk = b * Nc + t * 8 + i;
        if ((m[i] >> 8) & 1) {
            const int e = (m[i] >> 4) & 15;
            const int pos = base_e[e] + c[e]++;
            if (pos < CAPc) {
                const int slot = ((e * Bc + b) << 9) | pos;
                slot_token[slot] = tk;
                slot_gate[slot]  = g2[tk];
            }
        }
    }
}

// ---------------- loss reduction ----------------
__global__ __launch_bounds__(256) void reduce_stats_kernel(
    const float* __restrict__ raw, const int* __restrict__ meta,
    float* __restrict__ S, float* __restrict__ C)
{
    const int be = blockIdx.x, b = be >> 3, e = be & 7;
    float s = 0.f, c = 0.f;
    for (int n = threadIdx.x; n < Nc; n += 256) {
        const int tk = b * Nc + n;
        s += raw[(size_t)tk * 8 + e];
        c += ((meta[tk] & 15) == e) ? 1.f : 0.f;
    }
    __shared__ float sh_s[4], sh_c[4];
    const int lane = threadIdx.x & 63, wv = threadIdx.x >> 6;
#pragma unroll
    for (int off = 32; off; off >>= 1) { s += __shfl_down(s, off); c += __shfl_down(c, off); }
    if (lane == 0) { sh_s[wv] = s; sh_c[wv] = c; }
    __syncthreads();
    if (threadIdx.x == 0) {
        S[be] = sh_s[0] + sh_s[1] + sh_s[2] + sh_s[3];
        C[be] = sh_c[0] + sh_c[1] + sh_c[2] + sh_c[3];
    }
}

__global__ void loss_kernel(const float* __restrict__ S, const float* __restrict__ C,
                            float* __restrict__ dst)
{
    float v = S[threadIdx.x] * C[threadIdx.x];
#pragma unroll
    for (int off = 32; off; off >>= 1) v += __shfl_down(v, off);
    if (threadIdx.x == 0) *dst = v * (0.01f / ((float)Nc * (float)Nc));
}

// ---------------- weight transpose + bf16 convert ----------------
template <int R, int C>
__global__ __launch_bounds__(256) void transpose_kernel(
    const float* __restrict__ w, u16* __restrict__ wT, const int e0)
{
    __shared__ float tile[32][33];
    const int ez = blockIdx.z;
    const int c0 = blockIdx.x * 32, r0 = blockIdx.y * 32;
    const float* src = w + (size_t)(e0 + ez) * R * C;
    u16* dst = wT + (size_t)ez * C * R;
    const int t = threadIdx.x;
#pragma unroll
    for (int i = 0; i < 4; ++i) {
        const int r = i * 8 + (t >> 5), cc = t & 31;
        tile[r][cc] = src[(size_t)(r0 + r) * C + c0 + cc];
    }
    __syncthreads();
#pragma unroll
    for (int i = 0; i < 4; ++i) {
        const int cc = i * 8 + (t >> 5), r = t & 31;
        dst[(size_t)(c0 + cc) * R + r0 + r] = f2bf(tile[r][cc]);
    }
}

// ---------------- gather tokens into expert-slot rows (bf16) ----------------
__global__ __launch_bounds__(256) void gather_kernel(
    const float* __restrict__ x, const int* __restrict__ slot_token,
    u16* __restrict__ ei, const int slot0)
{
    const int s = blockIdx.x * 4 + (threadIdx.x >> 6);
    const int lane = threadIdx.x & 63;
    const int tk = slot_token[slot0 + s];
    uint4* dst = (uint4*)(ei + ((size_t)s << 10)) + lane * 2;
    if (tk < 0) {
        uint4 z = {0u, 0u, 0u, 0u};
        dst[0] = z; dst[1] = z;
    } else {
        const float4* src = (const float4*)(x + ((size_t)tk << 10)) + lane * 4;
        float4 v0 = src[0], v1 = src[1], v2 = src[2], v3 = src[3];
        uint4 o0, o1;
        o0.x = pack2(v0.x, v0.y); o0.y = pack2(v0.z, v0.w);
        o0.z = pack2(v1.x, v1.y); o0.w = pack2(v1.z, v1.w);
        o1.x = pack2(v2.x, v2.y); o1.y = pack2(v2.z, v2.w);
        o1.z = pack2(v3.x, v3.y); o1.w = pack2(v3.z, v3.w);
        dst[0] = o0; dst[1] = o1;
    }
}

// ---------------- ring-4 counted-vmcnt 256x256 bf16 MFMA GEMM ----------------
// C[M,ldc] = A[M,K] * Bt[e][nB,K]^T.  8 waves (2Mx4N), per-wave 128x64 output.
// BK=32, ring of 4 LDS tile-buffers (128 KiB), depth-3 prefetch,
// counted s_waitcnt vmcnt(8) so 2 tiles of loads stay in flight across
// RAW s_barrier (T4).  T2: XOR slot swizzle (pre-swizzled global source +
// swizzled ds_read; linear global_load_lds dest).  T5: setprio around MFMA.

constexpr int TSZ = 256 * 32;   // elements per tile buffer (16 KiB)

template <int K>
__device__ inline void stage32(const u16* __restrict__ Ab, const u16* __restrict__ Bb,
                               u16* As, u16* Bs, const int k0, const int tid)
{
    // thread tid writes LDS elems [tid*8, tid*8+8) (pass0 row tid>>2, phys slot tid&3)
    // and [4096+tid*8, ...) (pass1 row 128+(tid>>2)).
    // inverse swizzle: phys slot s holds global slot s ^ ((row>>1)&3).
    const int r0 = tid >> 2;
    const int gc = ((tid & 3) ^ ((tid >> 3) & 3)) * 8;
    GLDS16(Ab + (size_t)r0 * K + k0 + gc,           As + tid * 8);
    GLDS16(Ab + (size_t)(128 + r0) * K + k0 + gc,   As + 4096 + tid * 8);
    GLDS16(Bb + (size_t)r0 * K + k0 + gc,           Bs + tid * 8);
    GLDS16(Bb + (size_t)(128 + r0) * K + k0 + gc,   Bs + 4096 + tid * 8);
}

__device__ inline void compute32(const u16* At, const u16* Bt_,
                                 const int wr, const int wc, const int lr, const int lk,
                                 f32x4 acc[8][4])
{
    const int sl = (lk ^ ((lr >> 1) & 3)) * 8;   // swizzled slot (rows differ only in lr bits 1-2)
    short8 b[4];
#pragma unroll
    for (int fn = 0; fn < 4; ++fn)
        b[fn] = *(const short8*)(Bt_ + (wc * 64 + fn * 16 + lr) * 32 + sl);
#pragma unroll
    for (int fm = 0; fm < 8; ++fm) {
        short8 a = *(const short8*)(At + (wr * 128 + fm * 16 + lr) * 32 + sl);
#pragma unroll
        for (int fn = 0; fn < 4; ++fn)
            acc[fm][fn] = __builtin_amdgcn_mfma_f32_16x16x32_bf16(a, b[fn], acc[fm][fn], 0, 0, 0);
    }
}

template <int K, bool GELU, bool SCATTER>
__device__ inline void gemm_body(
    const u16* __restrict__ A, const u16* __restrict__ Bt, u16* __restrict__ Cc,
    float* __restrict__ outf, const int* __restrict__ slot_token,
    const float* __restrict__ slot_gate, const int slot_base,
    const int nB, const int ldc)
{
    __shared__ u16 As[4][TSZ];   // 64 KiB
    __shared__ u16 Bs[4][TSZ];   // 64 KiB

    const int tid = threadIdx.x;
    const int wv = tid >> 6, lane = tid & 63;
    const int m0 = blockIdx.x * 256, n0 = blockIdx.y * 256;
    const int e = blockIdx.x >> 4;    // 16 m-tiles (4096 rows) per expert
    const u16* Ab = A + (size_t)m0 * K;
    const u16* Bb = Bt + ((size_t)e * nB + n0) * K;

    const int wr = wv >> 2, wc = wv & 3;
    const int lr = lane & 15, lk = lane >> 4;

    f32x4 acc[8][4];
#pragma unroll
    for (int i = 0; i < 8; ++i)
#pragma unroll
        for (int j = 0; j < 4; ++j) acc[i][j] = (f32x4)0.f;

    constexpr int NT = K / 32;
    // prologue: prefetch tiles 0,1,2
    stage32<K>(Ab, Bb, As[0], Bs[0], 0, tid);
    stage32<K>(Ab, Bb, As[1], Bs[1], 32, tid);
    stage32<K>(Ab, Bb, As[2], Bs[2], 64, tid);
    asm volatile("s_waitcnt vmcnt(8)" ::: "memory");   // tile 0 landed (8 = tiles 1,2 in flight)
    __builtin_amdgcn_s_barrier();

    for (int t = 0; t < NT; ++t) {
        if (t + 3 < NT)
            stage32<K>(Ab, Bb, As[(t + 3) & 3], Bs[(t + 3) & 3], (t + 3) * 32, tid);
        __builtin_amdgcn_s_setprio(1);
        compute32(As[t & 3], Bs[t & 3], wr, wc, lr, lk, acc);
        __builtin_amdgcn_s_setprio(0);
        if (t < NT - 1) {
            // wait for tile t+1 only; keep younger tiles' loads in flight (T4)
            if (t + 3 < NT)      asm volatile("s_waitcnt vmcnt(8) lgkmcnt(0)" ::: "memory");
            else if (t + 2 < NT) asm volatile("s_waitcnt vmcnt(4) lgkmcnt(0)" ::: "memory");
            else                 asm volatile("s_waitcnt vmcnt(0) lgkmcnt(0)" ::: "memory");
            __builtin_amdgcn_s_barrier();
        }
    }

#pragma unroll
    for (int fm = 0; fm < 8; ++fm) {
        const int row = m0 + wr * 128 + fm * 16 + lk * 4;
        if (SCATTER) {
            int tks[4]; float gs[4];
#pragma unroll
            for (int r = 0; r < 4; ++r) {
                const int sg = slot_base + row + r;
                tks[r] = slot_token[sg];
                gs[r]  = slot_gate[sg];
            }
#pragma unroll
            for (int fn = 0; fn < 4; ++fn) {
                const int col = n0 + wc * 64 + fn * 16 + lr;
#pragma unroll
                for (int r = 0; r < 4; ++r) {
                    if (tks[r] >= 0)
                        unsafeAtomicAdd(outf + ((size_t)tks[r] << 10) + col,
                                        gs[r] * acc[fm][fn][r]);
                }
            }
        } else {
#pragma unroll
            for (int fn = 0; fn < 4; ++fn) {
                const int col = n0 + wc * 64 + fn * 16 + lr;
#pragma unroll
                for (int r = 0; r < 4; ++r) {
                    float v = acc[fm][fn][r];
                    if (GELU) v = 0.5f * v * (1.f + erff(v * 0.70710678118654752f));
                    Cc[(size_t)(row + r) * ldc + col] = f2bf(v);
                }
            }
        }
    }
}

__global__ __launch_bounds__(512, 2) void gemm1_kernel(
    const u16* __restrict__ A, const u16* __restrict__ Bt, u16* __restrict__ Cc)
{
    gemm_body<DIMc, true, false>(A, Bt, Cc, nullptr, nullptr, nullptr, 0, HIDc, HIDc);
}

__global__ __launch_bounds__(512, 2) void gemm2_kernel(
    const u16* __restrict__ A, const u16* __restrict__ Bt, float* __restrict__ outf,
    const int* __restrict__ slot_token, const float* __restrict__ slot_gate,
    const int slot_base)
{
    gemm_body<HIDc, false, true>(A, Bt, nullptr, outf, slot_token, slot_gate,
                                 slot_base, DIMc, DIMc);
}

// ---------------- launch ----------------
extern "C" void kernel_launch(void* const* d_in, const int* in_sizes, int n_in,
                              void* d_out, int out_size, void* d_ws, size_t ws_size,
                              hipStream_t stream)
{
    (void)in_sizes; (void)n_in; (void)out_size;

    const float* x  = (const float*)d_in[0];
    const float* wg = (const float*)d_in[1];
    const float* w1 = (const float*)d_in[2];
    const float* w2 = (const float*)d_in[3];
    const float* rp = (const float*)d_in[4];
    float* out = (float*)d_out;
    char* ws = (char*)d_ws;

    int epr = 8;
    while (epr > 1 && MISC_END + (size_t)epr * SZ_PER_E > ws_size) epr >>= 1;
    if (MISC_END + SZ_PER_E > ws_size) return;

    int* slot_token = (int*)(ws + OFF_SLOTTOK);
    float* slot_gate = (float*)(ws + OFF_SGATE);
    float* g1 = (float*)(ws + OFF_G1);
    float* g2 = (float*)(ws + OFF_G2);
    int* meta = (int*)(ws + OFF_META);
    float* raw = (float*)(ws + OFF_RAW);
    float* Sr = (float*)(ws + OFF_S);
    float* C1 = (float*)(ws + OFF_C);

    u16* w1T = (u16*)(ws + MISC_END);
    u16* w2T = (u16*)(ws + MISC_END + (size_t)epr * SZ_W1T_E);
    u16* ei  = (u16*)(ws + MISC_END + (size_t)epr * (SZ_W1T_E + SZ_W2T_E));
    u16* hid = (u16*)(ws + MISC_END + (size_t)epr * (SZ_W1T_E + SZ_W2T_E + SZ_EI_E));

    zero_out_kernel<<<(size_t)NTOK * DIMc / 1024, 256, 0, stream>>>(out);
    init_slots_kernel<<<NSLOT / 1024, 256, 0, stream>>>(slot_token);
    gate_kernel<<<NTOK / 4, 256, 0, stream>>>(x, wg, rp, raw, g1, g2, meta);
    scan_kernel<<<Bc, 256, 0, stream>>>(meta, g1, g2, slot_token, slot_gate);
    reduce_stats_kernel<<<64, 256, 0, stream>>>(raw, meta, Sr, C1);
    loss_kernel<<<1, 64, 0, stream>>>(Sr, C1, out + (size_t)NTOK * DIMc);

    for (int e0 = 0; e0 < Ec; e0 += epr) {
        transpose_kernel<DIMc, HIDc><<<dim3(HIDc / 32, DIMc / 32, epr), 256, 0, stream>>>(
            w1, w1T, e0);
        transpose_kernel<HIDc, DIMc><<<dim3(DIMc / 32, HIDc / 32, epr), 256, 0, stream>>>(
            w2, w2T, e0);
        gather_kernel<<<epr * SLOTPE / 4, 256, 0, stream>>>(x, slot_token, ei, e0 * SLOTPE);

        gemm1_kernel<<<dim3(epr * 16, HIDc / 256), 512, 0, stream>>>(ei, w1T, hid);
        gemm2_kernel<<<dim3(epr * 16, DIMc / 256), 512, 0, stream>>>(
            hid, w2T, out, slot_token, slot_gate, e0 * SLOTPE);
    }
}

// Round 5
// 622.351 us; speedup vs baseline: 1.1993x; 1.0841x over previous
//
#include <hip/hip_runtime.h>
#include <hip/hip_bf16.h>

typedef unsigned short u16;
typedef unsigned int u32;

typedef short short8 __attribute__((ext_vector_type(8)));
typedef float f32x4 __attribute__((ext_vector_type(4)));

// ---------------- problem constants ----------------
constexpr int Bc   = 8;
constexpr int Nc   = 2048;
constexpr int DIMc = 1024;
constexpr int Ec   = 8;
constexpr int HIDc = 2048;
constexpr int CAPc = 512;
constexpr int NTOK   = Bc * Nc;        // 16384
constexpr int SLOTPE = Bc * CAPc;      // 4096 slots per expert
constexpr int NSLOT  = Ec * SLOTPE;    // 32768

// ---------------- misc ws layout (bytes, fixed 1 MiB block) ----------------
constexpr size_t OFF_SLOTTOK = 0;
constexpr size_t OFF_SGATE   = OFF_SLOTTOK + (size_t)NSLOT * 4;
constexpr size_t OFF_G1      = OFF_SGATE + (size_t)NSLOT * 4;
constexpr size_t OFF_G2      = OFF_G1 + (size_t)NTOK * 4;
constexpr size_t OFF_META    = OFF_G2 + (size_t)NTOK * 4;
constexpr size_t OFF_RAW     = OFF_META + (size_t)NTOK * 4;
constexpr size_t OFF_S       = OFF_RAW + (size_t)NTOK * 8 * 4;
constexpr size_t OFF_C       = OFF_S + 64 * 4;
constexpr size_t MISC_END    = 1 << 20;
static_assert(OFF_C + 64 * 4 <= MISC_END, "misc overflow");

constexpr size_t SZ_W1T_E = (size_t)HIDc * DIMc * 2;    // 4 MiB
constexpr size_t SZ_W2T_E = (size_t)DIMc * HIDc * 2;    // 4 MiB
constexpr size_t SZ_EI_E  = (size_t)SLOTPE * DIMc * 2;  // 8 MiB
constexpr size_t SZ_HID_E = (size_t)SLOTPE * HIDc * 2;  // 16 MiB
constexpr size_t SZ_PER_E = SZ_W1T_E + SZ_W2T_E + SZ_EI_E + SZ_HID_E; // 32 MiB

// ---------------- helpers ----------------
__device__ inline u16 f2bf(float f) {
    u32 u = __float_as_uint(f);
    u32 r = (u + 0x7fffu + ((u >> 16) & 1u)) >> 16;
    return (u16)r;
}
__device__ inline u32 pack2(float lo, float hi) {
    return (u32)f2bf(lo) | ((u32)f2bf(hi) << 16);
}

#define GLDS16(gp, lp)                                                          \
    __builtin_amdgcn_global_load_lds(                                          \
        (const __attribute__((address_space(1))) void*)(gp),                   \
        (__attribute__((address_space(3))) void*)(lp), 16, 0, 0)

// ---------------- zero d_out ----------------
__global__ __launch_bounds__(256) void zero_out_kernel(float* __restrict__ p) {
    const size_t i = ((size_t)blockIdx.x * 256 + threadIdx.x) * 4;
    float4 z = {0.f, 0.f, 0.f, 0.f};
    *(float4*)(p + i) = z;
}

// ---------------- init slot map ----------------
__global__ __launch_bounds__(256) void init_slots_kernel(int* __restrict__ slot_token) {
    int i = (blockIdx.x * 256 + threadIdx.x) * 4;
    slot_token[i] = -1; slot_token[i + 1] = -1; slot_token[i + 2] = -1; slot_token[i + 3] = -1;
}

// ---------------- gating: one wave per token ----------------
__global__ __launch_bounds__(256) void gate_kernel(
    const float* __restrict__ x, const float* __restrict__ wg,
    const float* __restrict__ rp, float* __restrict__ raw_out,
    float* __restrict__ g1_out, float* __restrict__ g2_out, int* __restrict__ meta_out)
{
    const int tk   = blockIdx.x * 4 + (threadIdx.x >> 6);
    const int lane = threadIdx.x & 63;
    const float* xr = x + (size_t)tk * DIMc;

    float acc[8] = {0.f, 0.f, 0.f, 0.f, 0.f, 0.f, 0.f, 0.f};
#pragma unroll
    for (int i = 0; i < 4; ++i) {
        const int d0 = i * 256 + lane * 4;
        float4 xv = *(const float4*)(xr + d0);
#pragma unroll
        for (int j = 0; j < 4; ++j) {
            float xs = (&xv.x)[j];
            float4 w0 = *(const float4*)(wg + (size_t)(d0 + j) * 8);
            float4 w1 = *(const float4*)(wg + (size_t)(d0 + j) * 8 + 4);
            acc[0] += xs * w0.x; acc[1] += xs * w0.y; acc[2] += xs * w0.z; acc[3] += xs * w0.w;
            acc[4] += xs * w1.x; acc[5] += xs * w1.y; acc[6] += xs * w1.z; acc[7] += xs * w1.w;
        }
    }
#pragma unroll
    for (int e = 0; e < 8; ++e) {
#pragma unroll
        for (int off = 1; off < 64; off <<= 1) acc[e] += __shfl_xor(acc[e], off);
    }

    if (lane == 0) {
        float mx = acc[0];
#pragma unroll
        for (int e = 1; e < 8; ++e) mx = fmaxf(mx, acc[e]);
        float ex[8], s = 0.f;
#pragma unroll
        for (int e = 0; e < 8; ++e) { ex[e] = expf(acc[e] - mx); s += ex[e]; }
        float inv = 1.f / s;
        float raw[8];
#pragma unroll
        for (int e = 0; e < 8; ++e) raw[e] = ex[e] * inv;

        int i1 = 0; float g1 = raw[0];
#pragma unroll
        for (int e = 1; e < 8; ++e) if (raw[e] > g1) { g1 = raw[e]; i1 = e; }
        int i2 = -1; float g2 = -1.f;
#pragma unroll
        for (int e = 0; e < 8; ++e) if (e != i1 && raw[e] > g2) { g2 = raw[e]; i2 = e; }

        float denom = g1 + g2 + 1e-9f;
        float g1n = g1 / denom, g2n = g2 / denom;
        int keep = (rp[tk] < (g2n / 0.2f)) ? 1 : 0;

        float* ro = raw_out + (size_t)tk * 8;
#pragma unroll
        for (int e = 0; e < 8; ++e) ro[e] = raw[e];
        g1_out[tk] = g1n;
        g2_out[tk] = g2n;
        meta_out[tk] = i1 | (i2 << 4) | (keep << 8);
    }
}

// ---------------- per-batch capacity scan ----------------
__global__ __launch_bounds__(256) void scan_kernel(
    const int* __restrict__ meta, const float* __restrict__ g1, const float* __restrict__ g2,
    int* __restrict__ slot_token, float* __restrict__ slot_gate)
{
    const int b = blockIdx.x;
    const int t = threadIdx.x;
    __shared__ int cnt[256][8];
    __shared__ int base_e[8];

    int m[8];
#pragma unroll
    for (int i = 0; i < 8; ++i) m[i] = meta[b * Nc + t * 8 + i];

    int c[8] = {0, 0, 0, 0, 0, 0, 0, 0};
#pragma unroll
    for (int i = 0; i < 8; ++i) c[m[i] & 15]++;
#pragma unroll
    for (int e = 0; e < 8; ++e) cnt[t][e] = c[e];
    __syncthreads();
    if (t < 8) {
        int run = 0;
        for (int i = 0; i < 256; ++i) { int v = cnt[i][t]; cnt[i][t] = run; run += v; }
        base_e[t] = run < CAPc ? run : CAPc;
    }
    __syncthreads();
#pragma unroll
    for (int e = 0; e < 8; ++e) c[e] = cnt[t][e];
#pragma unroll
    for (int i = 0; i < 8; ++i) {
        const int tk = b * Nc + t * 8 + i;
        const int e = m[i] & 15;
        const int pos = c[e]++;
        if (pos < CAPc) {
            const int slot = ((e * Bc + b) << 9) | pos;
            slot_token[slot] = tk;
            slot_gate[slot]  = g1[tk];
        }
    }
    __syncthreads();

#pragma unroll
    for (int e = 0; e < 8; ++e) c[e] = 0;
#pragma unroll
    for (int i = 0; i < 8; ++i) {
        if ((m[i] >> 8) & 1) c[(m[i] >> 4) & 15]++;
    }
#pragma unroll
    for (int e = 0; e < 8; ++e) cnt[t][e] = c[e];
    __syncthreads();
    if (t < 8) {
        int run = 0;
        for (int i = 0; i < 256; ++i) { int v = cnt[i][t]; cnt[i][t] = run; run += v; }
    }
    __syncthreads();
#pragma unroll
    for (int e = 0; e < 8; ++e) c[e] = cnt[t][e];
#pragma unroll
    for (int i = 0; i < 8; ++i) {
        const int tk = b * Nc + t * 8 + i;
        if ((m[i] >> 8) & 1) {
            const int e = (m[i] >> 4) & 15;
            const int pos = base_e[e] + c[e]++;
            if (pos < CAPc) {
                const int slot = ((e * Bc + b) << 9) | pos;
                slot_token[slot] = tk;
                slot_gate[slot]  = g2[tk];
            }
        }
    }
}

// ---------------- loss reduction ----------------
__global__ __launch_bounds__(256) void reduce_stats_kernel(
    const float* __restrict__ raw, const int* __restrict__ meta,
    float* __restrict__ S, float* __restrict__ C)
{
    const int be = blockIdx.x, b = be >> 3, e = be & 7;
    float s = 0.f, c = 0.f;
    for (int n = threadIdx.x; n < Nc; n += 256) {
        const int tk = b * Nc + n;
        s += raw[(size_t)tk * 8 + e];
        c += ((meta[tk] & 15) == e) ? 1.f : 0.f;
    }
    __shared__ float sh_s[4], sh_c[4];
    const int lane = threadIdx.x & 63, wv = threadIdx.x >> 6;
#pragma unroll
    for (int off = 32; off; off >>= 1) { s += __shfl_down(s, off); c += __shfl_down(c, off); }
    if (lane == 0) { sh_s[wv] = s; sh_c[wv] = c; }
    __syncthreads();
    if (threadIdx.x == 0) {
        S[be] = sh_s[0] + sh_s[1] + sh_s[2] + sh_s[3];
        C[be] = sh_c[0] + sh_c[1] + sh_c[2] + sh_c[3];
    }
}

__global__ void loss_kernel(const float* __restrict__ S, const float* __restrict__ C,
                            float* __restrict__ dst)
{
    float v = S[threadIdx.x] * C[threadIdx.x];
#pragma unroll
    for (int off = 32; off; off >>= 1) v += __shfl_down(v, off);
    if (threadIdx.x == 0) *dst = v * (0.01f / ((float)Nc * (float)Nc));
}

// ---------------- weight transpose + bf16 convert ----------------
template <int R, int C>
__global__ __launch_bounds__(256) void transpose_kernel(
    const float* __restrict__ w, u16* __restrict__ wT, const int e0)
{
    __shared__ float tile[32][33];
    const int ez = blockIdx.z;
    const int c0 = blockIdx.x * 32, r0 = blockIdx.y * 32;
    const float* src = w + (size_t)(e0 + ez) * R * C;
    u16* dst = wT + (size_t)ez * C * R;
    const int t = threadIdx.x;
#pragma unroll
    for (int i = 0; i < 4; ++i) {
        const int r = i * 8 + (t >> 5), cc = t & 31;
        tile[r][cc] = src[(size_t)(r0 + r) * C + c0 + cc];
    }
    __syncthreads();
#pragma unroll
    for (int i = 0; i < 4; ++i) {
        const int cc = i * 8 + (t >> 5), r = t & 31;
        dst[(size_t)(c0 + cc) * R + r0 + r] = f2bf(tile[r][cc]);
    }
}

// ---------------- gather tokens into expert-slot rows (bf16) ----------------
__global__ __launch_bounds__(256) void gather_kernel(
    const float* __restrict__ x, const int* __restrict__ slot_token,
    u16* __restrict__ ei, const int slot0)
{
    const int s = blockIdx.x * 4 + (threadIdx.x >> 6);
    const int lane = threadIdx.x & 63;
    const int tk = slot_token[slot0 + s];
    uint4* dst = (uint4*)(ei + ((size_t)s << 10)) + lane * 2;
    if (tk < 0) {
        uint4 z = {0u, 0u, 0u, 0u};
        dst[0] = z; dst[1] = z;
    } else {
        const float4* src = (const float4*)(x + ((size_t)tk << 10)) + lane * 4;
        float4 v0 = src[0], v1 = src[1], v2 = src[2], v3 = src[3];
        uint4 o0, o1;
        o0.x = pack2(v0.x, v0.y); o0.y = pack2(v0.z, v0.w);
        o0.z = pack2(v1.x, v1.y); o0.w = pack2(v1.z, v1.w);
        o1.x = pack2(v2.x, v2.y); o1.y = pack2(v2.z, v2.w);
        o1.z = pack2(v3.x, v3.y); o1.w = pack2(v3.z, v3.w);
        dst[0] = o0; dst[1] = o1;
    }
}

// ---------------- 8-phase 256x256 bf16 MFMA GEMM (m201-style template) ----------------
// C[M,ldc] = A[M,K] * Bt[e][nB,K]^T. 8 waves (2Mx4N), per-wave 128x64 output.
// K-tile BK=64 split into two 32-col halves; LDS [2 dbuf][2 kk][256x32] per matrix
// (128 KiB). Per K-tile: 4 phases of {ds_read frags; stage 1 half-tile (2 gl_lds);
// barrier; lgkmcnt(0)+sched_barrier; setprio(1); 16 MFMA; setprio(0); barrier}.
// Counted vmcnt(4) once per K-tile (2 newest half-tiles stay in flight).
// Slot-XOR LDS swizzle (measured 0 bank conflicts in round 4 geometry).

constexpr int HTE = 256 * 32;   // half-tile elements (16 KiB)

__device__ inline const short8* fragp(const u16* half, const int row, const int lk) {
    return (const short8*)(half + row * 32 + ((lk ^ ((row >> 1) & 3)) << 3));
}

template <int K>
__device__ inline void stage_half(const u16* __restrict__ g, u16* lds,
                                  const int kbase, const int tid)
{
    const int gc = (((tid & 3) ^ ((tid >> 3) & 3)) << 3);
#pragma unroll
    for (int j = 0; j < 2; ++j) {
        const int idx = j * 512 + tid;
        GLDS16(g + (size_t)(idx >> 2) * K + kbase + gc, lds + idx * 8);
    }
}

#define PHASE_SYNC_PRE()                                       \
    asm volatile("" ::: "memory");                             \
    __builtin_amdgcn_s_barrier();                              \
    asm volatile("s_waitcnt lgkmcnt(0)" ::: "memory");         \
    __builtin_amdgcn_sched_barrier(0);                         \
    __builtin_amdgcn_s_setprio(1)

#define PHASE_SYNC_POST()                                      \
    __builtin_amdgcn_s_setprio(0);                             \
    __builtin_amdgcn_s_barrier()

template <int K, bool GELU, bool SCATTER>
__device__ inline void gemm_body(
    const u16* __restrict__ A, const u16* __restrict__ Bt, u16* __restrict__ Cc,
    float* __restrict__ outf, const int* __restrict__ slot_token,
    const float* __restrict__ slot_gate, const int slot_base,
    const int nB, const int ldc)
{
    __shared__ u16 As[4 * HTE];   // [buf*2 + kk]
    __shared__ u16 Bs[4 * HTE];

    const int tid = threadIdx.x;
    const int wv = tid >> 6, lane = tid & 63;

    // XCD-chunked blockIdx remap (nwg % 8 == 0 always here; gridDim.x pow2)
    const int nwg = gridDim.x * gridDim.y;
    const int bl  = blockIdx.y * gridDim.x + blockIdx.x;
    const int sid = (bl & 7) * (nwg >> 3) + (bl >> 3);
    const int lgx = __ffs(gridDim.x) - 1;
    const int mt = sid & (gridDim.x - 1), ntile = sid >> lgx;

    const int m0 = mt * 256, n0 = ntile * 256;
    const int e = mt >> 4;    // 16 m-tiles (4096 rows) per expert
    const u16* Ab = A + (size_t)m0 * K;
    const u16* Bb = Bt + ((size_t)e * nB + n0) * K;

    const int wr = wv >> 2, wc = wv & 3;
    const int lr = lane & 15, lk = lane >> 4;

    f32x4 acc[2][4][4];
#pragma unroll
    for (int h = 0; h < 2; ++h)
#pragma unroll
        for (int i = 0; i < 4; ++i)
#pragma unroll
            for (int j = 0; j < 4; ++j) acc[h][i][j] = (f32x4)0.f;

    constexpr int NT = K / 64;

    // prologue: tile0 (kk0,kk1) + tile1 (kk0); allow 2 newest half-tiles in flight
    stage_half<K>(Ab, As + 0 * HTE, 0, tid);
    stage_half<K>(Bb, Bs + 0 * HTE, 0, tid);
    stage_half<K>(Ab, As + 1 * HTE, 32, tid);
    stage_half<K>(Bb, Bs + 1 * HTE, 32, tid);
    stage_half<K>(Ab, As + 2 * HTE, 64, tid);
    stage_half<K>(Bb, Bs + 2 * HTE, 64, tid);
    asm volatile("s_waitcnt vmcnt(4)" ::: "memory");
    __builtin_amdgcn_s_barrier();

#pragma unroll 2
    for (int T = 0; T < NT; ++T) {
        const int buf = T & 1;
        const u16* A0 = As + buf * 2 * HTE;
        const u16* A1 = A0 + HTE;
        const u16* B0 = Bs + buf * 2 * HTE;
        const u16* B1 = B0 + HTE;
        u16* AsN = As + (buf ^ 1) * 2 * HTE;
        u16* BsN = Bs + (buf ^ 1) * 2 * HTE;
        const bool s1 = (T + 1 < NT);
        const bool s2 = (T + 2 < NT);

        short8 a[4], b0r[4], b1r[4];

        // ---- phase 1: kk0, fm 0-3 ---- (reads 8, stages A[T+1]kk1)
#pragma unroll
        for (int fn = 0; fn < 4; ++fn) b0r[fn] = *fragp(B0, wc * 64 + fn * 16 + lr, lk);
#pragma unroll
        for (int fi = 0; fi < 4; ++fi) a[fi] = *fragp(A0, wr * 128 + fi * 16 + lr, lk);
        if (s1) stage_half<K>(Ab, AsN + HTE, (T + 1) * 64 + 32, tid);
        PHASE_SYNC_PRE();
#pragma unroll
        for (int fi = 0; fi < 4; ++fi)
#pragma unroll
            for (int fn = 0; fn < 4; ++fn)
                acc[0][fi][fn] = __builtin_amdgcn_mfma_f32_16x16x32_bf16(
                    a[fi], b0r[fn], acc[0][fi][fn], 0, 0, 0);
        PHASE_SYNC_POST();

        // ---- phase 2: kk0, fm 4-7 ---- (reads 4, stages B[T+1]kk1)
#pragma unroll
        for (int fi = 0; fi < 4; ++fi) a[fi] = *fragp(A0, wr * 128 + 64 + fi * 16 + lr, lk);
        if (s1) stage_half<K>(Bb, BsN + HTE, (T + 1) * 64 + 32, tid);
        PHASE_SYNC_PRE();
#pragma unroll
        for (int fi = 0; fi < 4; ++fi)
#pragma unroll
            for (int fn = 0; fn < 4; ++fn)
                acc[1][fi][fn] = __builtin_amdgcn_mfma_f32_16x16x32_bf16(
                    a[fi], b0r[fn], acc[1][fi][fn], 0, 0, 0);
        PHASE_SYNC_POST();

        // ---- phase 3: kk1, fm 0-3 ---- (reads 8, stages A[T+2]kk0 over A0)
#pragma unroll
        for (int fn = 0; fn < 4; ++fn) b1r[fn] = *fragp(B1, wc * 64 + fn * 16 + lr, lk);
#pragma unroll
        for (int fi = 0; fi < 4; ++fi) a[fi] = *fragp(A1, wr * 128 + fi * 16 + lr, lk);
        if (s2) stage_half<K>(Ab, (u16*)A0, (T + 2) * 64, tid);
        PHASE_SYNC_PRE();
#pragma unroll
        for (int fi = 0; fi < 4; ++fi)
#pragma unroll
            for (int fn = 0; fn < 4; ++fn)
                acc[0][fi][fn] = __builtin_amdgcn_mfma_f32_16x16x32_bf16(
                    a[fi], b1r[fn], acc[0][fi][fn], 0, 0, 0);
        PHASE_SYNC_POST();

        // ---- phase 4: kk1, fm 4-7 ---- (reads 4, stages B[T+2]kk0 over B0)
#pragma unroll
        for (int fi = 0; fi < 4; ++fi) a[fi] = *fragp(A1, wr * 128 + 64 + fi * 16 + lr, lk);
        if (s2) stage_half<K>(Bb, (u16*)B0, (T + 2) * 64, tid);
        asm volatile("" ::: "memory");
        __builtin_amdgcn_s_barrier();
        asm volatile("s_waitcnt lgkmcnt(0)" ::: "memory");
        __builtin_amdgcn_sched_barrier(0);
        __builtin_amdgcn_s_setprio(1);
#pragma unroll
        for (int fi = 0; fi < 4; ++fi)
#pragma unroll
            for (int fn = 0; fn < 4; ++fn)
                acc[1][fi][fn] = __builtin_amdgcn_mfma_f32_16x16x32_bf16(
                    a[fi], b1r[fn], acc[1][fi][fn], 0, 0, 0);
        __builtin_amdgcn_s_setprio(0);
        if (T < NT - 1) {
            // K-tile boundary: force tile T+1 landed; keep T+2's kk0 (2 half-tiles) in flight
            if (s2) asm volatile("s_waitcnt vmcnt(4)" ::: "memory");
            else    asm volatile("s_waitcnt vmcnt(0)" ::: "memory");
            __builtin_amdgcn_s_barrier();
        }
    }

#pragma unroll
    for (int fmh = 0; fmh < 2; ++fmh)
#pragma unroll
    for (int fi = 0; fi < 4; ++fi) {
        const int row = m0 + wr * 128 + fmh * 64 + fi * 16 + lk * 4;
        if (SCATTER) {
            int tks[4]; float gs[4];
#pragma unroll
            for (int r = 0; r < 4; ++r) {
                const int sg = slot_base + row + r;
                tks[r] = slot_token[sg];
                gs[r]  = slot_gate[sg];
            }
#pragma unroll
            for (int fn = 0; fn < 4; ++fn) {
                const int col = n0 + wc * 64 + fn * 16 + lr;
#pragma unroll
                for (int r = 0; r < 4; ++r) {
                    if (tks[r] >= 0)
                        unsafeAtomicAdd(outf + ((size_t)tks[r] << 10) + col,
                                        gs[r] * acc[fmh][fi][fn][r]);
                }
            }
        } else {
#pragma unroll
            for (int fn = 0; fn < 4; ++fn) {
                const int col = n0 + wc * 64 + fn * 16 + lr;
#pragma unroll
                for (int r = 0; r < 4; ++r) {
                    float v = acc[fmh][fi][fn][r];
                    if (GELU) v = 0.5f * v * (1.f + erff(v * 0.70710678118654752f));
                    Cc[(size_t)(row + r) * ldc + col] = f2bf(v);
                }
            }
        }
    }
}

__global__ __launch_bounds__(512, 2) void gemm1_kernel(
    const u16* __restrict__ A, const u16* __restrict__ Bt, u16* __restrict__ Cc)
{
    gemm_body<DIMc, true, false>(A, Bt, Cc, nullptr, nullptr, nullptr, 0, HIDc, HIDc);
}

__global__ __launch_bounds__(512, 2) void gemm2_kernel(
    const u16* __restrict__ A, const u16* __restrict__ Bt, float* __restrict__ outf,
    const int* __restrict__ slot_token, const float* __restrict__ slot_gate,
    const int slot_base)
{
    gemm_body<HIDc, false, true>(A, Bt, nullptr, outf, slot_token, slot_gate,
                                 slot_base, DIMc, DIMc);
}

// ---------------- launch ----------------
extern "C" void kernel_launch(void* const* d_in, const int* in_sizes, int n_in,
                              void* d_out, int out_size, void* d_ws, size_t ws_size,
                              hipStream_t stream)
{
    (void)in_sizes; (void)n_in; (void)out_size;

    const float* x  = (const float*)d_in[0];
    const float* wg = (const float*)d_in[1];
    const float* w1 = (const float*)d_in[2];
    const float* w2 = (const float*)d_in[3];
    const float* rp = (const float*)d_in[4];
    float* out = (float*)d_out;
    char* ws = (char*)d_ws;

    int epr = 8;
    while (epr > 1 && MISC_END + (size_t)epr * SZ_PER_E > ws_size) epr >>= 1;
    if (MISC_END + SZ_PER_E > ws_size) return;

    int* slot_token = (int*)(ws + OFF_SLOTTOK);
    float* slot_gate = (float*)(ws + OFF_SGATE);
    float* g1 = (float*)(ws + OFF_G1);
    float* g2 = (float*)(ws + OFF_G2);
    int* meta = (int*)(ws + OFF_META);
    float* raw = (float*)(ws + OFF_RAW);
    float* Sr = (float*)(ws + OFF_S);
    float* C1 = (float*)(ws + OFF_C);

    u16* w1T = (u16*)(ws + MISC_END);
    u16* w2T = (u16*)(ws + MISC_END + (size_t)epr * SZ_W1T_E);
    u16* ei  = (u16*)(ws + MISC_END + (size_t)epr * (SZ_W1T_E + SZ_W2T_E));
    u16* hid = (u16*)(ws + MISC_END + (size_t)epr * (SZ_W1T_E + SZ_W2T_E + SZ_EI_E));

    zero_out_kernel<<<(size_t)NTOK * DIMc / 1024, 256, 0, stream>>>(out);
    init_slots_kernel<<<NSLOT / 1024, 256, 0, stream>>>(slot_token);
    gate_kernel<<<NTOK / 4, 256, 0, stream>>>(x, wg, rp, raw, g1, g2, meta);
    scan_kernel<<<Bc, 256, 0, stream>>>(meta, g1, g2, slot_token, slot_gate);
    reduce_stats_kernel<<<64, 256, 0, stream>>>(raw, meta, Sr, C1);
    loss_kernel<<<1, 64, 0, stream>>>(Sr, C1, out + (size_t)NTOK * DIMc);

    for (int e0 = 0; e0 < Ec; e0 += epr) {
        transpose_kernel<DIMc, HIDc><<<dim3(HIDc / 32, DIMc / 32, epr), 256, 0, stream>>>(
            w1, w1T, e0);
        transpose_kernel<HIDc, DIMc><<<dim3(DIMc / 32, HIDc / 32, epr), 256, 0, stream>>>(
            w2, w2T, e0);
        gather_kernel<<<epr * SLOTPE / 4, 256, 0, stream>>>(x, slot_token, ei, e0 * SLOTPE);

        gemm1_kernel<<<dim3(epr * 16, HIDc / 256), 512, 0, stream>>>(ei, w1T, hid);
        gemm2_kernel<<<dim3(epr * 16, DIMc / 256), 512, 0, stream>>>(
            hid, w2T, out, slot_token, slot_gate, e0 * SLOTPE);
    }
}